// Round 2
// baseline (1044.520 us; speedup 1.0000x reference)
//
#include <hip/hip_runtime.h>
#include <stdint.h>

#define SEQ   2048
#define HID   4096
#define NH    32
#define NKV   8
#define KVDIM 1024   // NKV*HD
#define KVCAT 2048   // KVDIM*2

typedef int v4i __attribute__((ext_vector_type(4)));

__device__ __forceinline__ float slot_scale(const unsigned* slots, int slot) {
    return fmaxf(__uint_as_float(slots[slot]) / 127.0f, 1e-8f);
}

__device__ __forceinline__ int q8v(float x, float s) {
    int v = (int)rintf(x / s);
    return v < -127 ? -127 : (v > 127 ? 127 : v);
}

__device__ __forceinline__ float fexp2(float x) {
    float r; asm("v_exp_f32 %0, %1" : "=v"(r) : "v"(x)); return r;
}

__device__ __forceinline__ float amax4(const float* __restrict__ p, long v) {
    float4 x = *(const float4*)(p + v * 4);
    return fmaxf(fmaxf(fabsf(x.x), fabsf(x.y)), fmaxf(fabsf(x.z), fabsf(x.w)));
}

__device__ __forceinline__ void wave_amax_atomic(float m, unsigned* slots, int slot,
                                                 int lane) {
    for (int off = 32; off; off >>= 1) m = fmaxf(m, __shfl_xor(m, off, 64));
    if (lane == 0) atomicMax(slots + slot, __float_as_uint(m));
}

// ---------------- fused absmax over the 5 f32 input tensors ----------------
__global__ void k_absmax5(const float* __restrict__ a0, const float* __restrict__ a1,
                          const float* __restrict__ a2, const float* __restrict__ a3,
                          const float* __restrict__ a4, unsigned* slots) {
    const long n0 = (long)SEQ * HID / 4, n1 = (long)HID * HID / 4, n2 = (long)KVDIM * HID / 4;
    const long e0 = n0, e1 = e0 + n1, e2 = e1 + n2, e3 = e2 + n2, e4 = e3 + n1;
    float m0 = 0, m1 = 0, m2 = 0, m3 = 0, m4 = 0;
    for (long v = blockIdx.x * (long)blockDim.x + threadIdx.x; v < e4;
         v += (long)gridDim.x * blockDim.x) {
        if (v < e0)      m0 = fmaxf(m0, amax4(a0, v));
        else if (v < e1) m1 = fmaxf(m1, amax4(a1, v - e0));
        else if (v < e2) m2 = fmaxf(m2, amax4(a2, v - e1));
        else if (v < e3) m3 = fmaxf(m3, amax4(a3, v - e2));
        else             m4 = fmaxf(m4, amax4(a4, v - e3));
    }
    int lane = threadIdx.x & 63;
    wave_amax_atomic(m0, slots, 0, lane);
    wave_amax_atomic(m1, slots, 1, lane);
    wave_amax_atomic(m2, slots, 2, lane);
    wave_amax_atomic(m3, slots, 3, lane);
    wave_amax_atomic(m4, slots, 4, lane);
}

__device__ __forceinline__ void qstore4(const float* __restrict__ src, long v,
                                        int8_t* __restrict__ dst, float s) {
    float4 x = *(const float4*)(src + v * 4);
    unsigned pa = (unsigned)(uint8_t)(int8_t)q8v(x.x, s)
                | ((unsigned)(uint8_t)(int8_t)q8v(x.y, s) << 8)
                | ((unsigned)(uint8_t)(int8_t)q8v(x.z, s) << 16)
                | ((unsigned)(uint8_t)(int8_t)q8v(x.w, s) << 24);
    *(unsigned*)(dst + v * 4) = pa;
}

// ---------------- fused quantize of hid, wq, wk, wv ----------------
__global__ void k_quant4(const float* __restrict__ a0, const float* __restrict__ a1,
                         const float* __restrict__ a2, const float* __restrict__ a3,
                         int8_t* __restrict__ d0, int8_t* __restrict__ d1,
                         int8_t* __restrict__ d2, int8_t* __restrict__ d3,
                         const unsigned* __restrict__ slots) {
    const long n0 = (long)SEQ * HID / 4, n1 = (long)HID * HID / 4, n2 = (long)KVDIM * HID / 4;
    const long e0 = n0, e1 = e0 + n1, e2 = e1 + n2, e3 = e2 + n2;
    float s0 = slot_scale(slots, 0), s1 = slot_scale(slots, 1);
    float s2 = slot_scale(slots, 2), s3 = slot_scale(slots, 3);
    for (long v = blockIdx.x * (long)blockDim.x + threadIdx.x; v < e3;
         v += (long)gridDim.x * blockDim.x) {
        if (v < e0)      qstore4(a0, v, d0, s0);
        else if (v < e1) qstore4(a1, v - e0, d1, s1);
        else if (v < e2) qstore4(a2, v - e1, d2, s2);
        else             qstore4(a3, v - e2, d3, s3);
    }
}

// ---------------- generic quantize f32 -> int8 (dst contiguous, src strided) ----------------
__global__ void k_quant(const float* __restrict__ x, int8_t* __restrict__ q, long nvec,
                        int rshift, long cmaskv, long ld,
                        const unsigned* __restrict__ slots, int slot) {
    float s = slot_scale(slots, slot);
    for (long vid = blockIdx.x * (long)blockDim.x + threadIdx.x; vid < nvec;
         vid += (long)gridDim.x * blockDim.x) {
        long r = vid >> rshift;
        long c = (vid & cmaskv) << 2;
        float4 v = *(const float4*)(x + r * ld + c);
        unsigned pa = (unsigned)(uint8_t)(int8_t)q8v(v.x, s)
                    | ((unsigned)(uint8_t)(int8_t)q8v(v.y, s) << 8)
                    | ((unsigned)(uint8_t)(int8_t)q8v(v.z, s) << 16)
                    | ((unsigned)(uint8_t)(int8_t)q8v(v.w, s) << 24);
        *(unsigned*)(q + vid * 4) = pa;
    }
}

// ---------------- rope cos/sin table ----------------
__global__ void k_ropetab(const int* __restrict__ pos, float* __restrict__ ct,
                          float* __restrict__ st) {
    int tid = blockIdx.x * blockDim.x + threadIdx.x;
    if (tid >= SEQ * 64) return;
    int i = tid & 63, s = tid >> 6;
    double inv = 1.0 / pow(10000.0, (double)((float)(2 * i) * (1.0f / 128.0f)));
    float invf = (float)inv;
    float angf = (float)pos[s] * invf;
    double a = (double)angf;
    ct[tid] = (float)cos(a);
    st[tid] = (float)sin(a);
}

// ---------------- rope in-place (float4) + absmax ----------------
__global__ void k_rope(float* __restrict__ x, long ld, int hbits,
                       const float* __restrict__ ct, const float* __restrict__ st,
                       unsigned* slots, int slot) {
    int t = blockIdx.x * blockDim.x + threadIdx.x;
    int i4 = t & 15;
    int h = (t >> 4) & ((1 << hbits) - 1);
    int s = t >> (4 + hbits);
    long base = (long)s * ld + h * 128 + i4 * 4;
    float4 a = *(float4*)(x + base);
    float4 b = *(float4*)(x + base + 64);
    float4 c = *(const float4*)(ct + s * 64 + i4 * 4);
    float4 sn = *(const float4*)(st + s * 64 + i4 * 4);
    float4 o0, o1;
    o0.x = a.x * c.x - b.x * sn.x;  o1.x = b.x * c.x + a.x * sn.x;
    o0.y = a.y * c.y - b.y * sn.y;  o1.y = b.y * c.y + a.y * sn.y;
    o0.z = a.z * c.z - b.z * sn.z;  o1.z = b.z * c.z + a.z * sn.z;
    o0.w = a.w * c.w - b.w * sn.w;  o1.w = b.w * c.w + a.w * sn.w;
    *(float4*)(x + base) = o0;
    *(float4*)(x + base + 64) = o1;
    float m = fmaxf(fmaxf(fmaxf(fabsf(o0.x), fabsf(o0.y)), fmaxf(fabsf(o0.z), fabsf(o0.w))),
                    fmaxf(fmaxf(fabsf(o1.x), fabsf(o1.y)), fmaxf(fabsf(o1.z), fabsf(o1.w))));
    wave_amax_atomic(m, slots, slot, threadIdx.x & 63);
}

// ---------------- transpose + quantize (V -> V^T int8) ----------------
__global__ void k_transq(const float* __restrict__ src, long lds_, int8_t* __restrict__ dst,
                         long ldd, const unsigned* __restrict__ slots, int slot) {
    __shared__ float t[32][33];
    float s = slot_scale(slots, slot);
    int bx = blockIdx.x, by = blockIdx.y;
    int tid = threadIdx.x;
    int c = tid & 31, r0 = tid >> 5;
    #pragma unroll
    for (int j = 0; j < 4; j++) {
        int r = r0 + j * 8;
        t[r][c] = src[(long)(by * 32 + r) * lds_ + bx * 32 + c];
    }
    __syncthreads();
    int d = tid >> 3, k4 = (tid & 7) * 4;
    unsigned pa = 0;
    #pragma unroll
    for (int j = 0; j < 4; j++) {
        int iv = q8v(t[k4 + j][d], s);
        pa |= ((unsigned)(uint8_t)(int8_t)iv) << (8 * j);
    }
    *(unsigned*)(dst + (long)(bx * 32 + d) * ldd + by * 32 + k4) = pa;
}

// ---------------- int8 GEMM: C[M][N] = sA*sB * (A[M][K] . B[N][K]^T) ----------------
// optional fused absmax over cols >= am_col0 into slots[am_slot]
__global__ __launch_bounds__(256) void k_gemm_i8(
    const int8_t* __restrict__ A, const int8_t* __restrict__ B, float* __restrict__ C,
    int M, int N, int K, unsigned* slots,
    int slotA, int slotB, int slotB2, int nsplit, int am_slot, int am_col0) {
    __shared__ int8_t As[128 * 128];
    __shared__ int8_t Bs[128 * 128];
    const v4i vzero = {0, 0, 0, 0};
    int tid = threadIdx.x, lane = tid & 63, wid = tid >> 6;
    int nbx = N >> 7;
    int nwg = gridDim.x, wg = blockIdx.x;
    int cpx = nwg >> 3;
    int swz = (wg & 7) * cpx + (wg >> 3);
    int bm = swz / nbx, bn = swz % nbx;
    long rowA0 = (long)bm * 128, colB0 = (long)bn * 128;
    int wrow = (wid >> 1) * 64, wcol = (wid & 1) * 64;
    v4i acc[4][4];
    #pragma unroll
    for (int m = 0; m < 4; m++)
        #pragma unroll
        for (int n = 0; n < 4; n++) acc[m][n] = vzero;
    for (int kt = 0; kt < K; kt += 128) {
        #pragma unroll
        for (int i = 0; i < 4; i++) {
            int chunk = tid + i * 256;
            int row = chunk >> 3, cc = chunk & 7;
            int sw = (cc ^ (row & 7)) * 16;
            v4i av = *(const v4i*)(A + (rowA0 + row) * K + kt + cc * 16);
            v4i bv = *(const v4i*)(B + (colB0 + row) * K + kt + cc * 16);
            *(v4i*)(As + row * 128 + sw) = av;
            *(v4i*)(Bs + row * 128 + sw) = bv;
        }
        __syncthreads();
        #pragma unroll
        for (int ks = 0; ks < 2; ks++) {
            v4i af[4], bf[4];
            #pragma unroll
            for (int m = 0; m < 4; m++) {
                int row = wrow + m * 16 + (lane & 15);
                af[m] = *(const v4i*)(As + row * 128 + (((ks * 4 + (lane >> 4)) ^ (row & 7)) * 16));
            }
            #pragma unroll
            for (int n = 0; n < 4; n++) {
                int row = wcol + n * 16 + (lane & 15);
                bf[n] = *(const v4i*)(Bs + row * 128 + (((ks * 4 + (lane >> 4)) ^ (row & 7)) * 16));
            }
            #pragma unroll
            for (int m = 0; m < 4; m++)
                #pragma unroll
                for (int n = 0; n < 4; n++)
                    acc[m][n] = __builtin_amdgcn_mfma_i32_16x16x64_i8(af[m], bf[n], acc[m][n], 0, 0, 0);
        }
        __syncthreads();
    }
    float sA = slot_scale(slots, slotA);
    float sB1 = slot_scale(slots, slotB);
    float sB2 = slot_scale(slots, slotB2);
    float am = 0.f;
    #pragma unroll
    for (int m = 0; m < 4; m++) {
        long row0 = rowA0 + wrow + m * 16 + ((lane >> 4) << 2);
        #pragma unroll
        for (int n = 0; n < 4; n++) {
            int col = (int)colB0 + wcol + n * 16 + (lane & 15);
            float sc = sA * ((col < nsplit) ? sB1 : sB2);
            float* cp = C + row0 * N + col;
            #pragma unroll
            for (int r = 0; r < 4; r++) {
                float val = sc * (float)acc[m][n][r];
                cp[(long)r * N] = val;
                if (col >= am_col0) am = fmaxf(am, fabsf(val));
            }
        }
    }
    if (am_slot >= 0) wave_amax_atomic(am, slots, am_slot, lane);
}

// ---------------- two-pass flash attention (int8, swapped QK^T, exp2-fast) ----------------
__global__ __launch_bounds__(256) void k_attn(
    const int8_t* __restrict__ Qq, const int8_t* __restrict__ Kq, const int8_t* __restrict__ Vtq,
    int* __restrict__ AO, unsigned* slots) {
    __shared__ int8_t Qs[64 * 128];   // reused as packed-P store in pass 2
    __shared__ int8_t Ks[64 * 128];
    __shared__ int8_t Vs[128 * 64];
    const v4i vzero = {0, 0, 0, 0};
    const int NEGS = -(1 << 29);
    int tid = threadIdx.x, lane = tid & 63, w = tid >> 6;
    int qlan = lane & 15, g = lane >> 4;
    int idx = blockIdx.x;
    int qb = 31 - (idx >> 5), h = idx & 31, kvh = h >> 2;   // long blocks first
    float sq = slot_scale(slots, 5), sk = slot_scale(slots, 6);
    float c2 = sq * sk * 0.08838834764831845f * 1.4426950408889634f;  // /sqrt(128)*log2(e)
    // stage Q (64x128, XOR-swizzled)
    #pragma unroll
    for (int i = 0; i < 2; i++) {
        int chunk = tid + i * 256;
        int row = chunk >> 3, cc = chunk & 7;
        v4i v = *(const v4i*)(Qq + (long)(qb * 64 + row) * HID + h * 128 + cc * 16);
        *(v4i*)(Qs + row * 128 + ((cc ^ (row & 7)) * 16)) = v;
    }
    __syncthreads();
    v4i aq[2];
    #pragma unroll
    for (int ks = 0; ks < 2; ks++) {
        int row = w * 16 + qlan;
        aq[ks] = *(const v4i*)(Qs + row * 128 + (((ks * 4 + g) ^ (row & 7)) * 16));
    }
    int mi = -(1 << 30);
    float l = 0.f;
    // ---- pass 1: int row-max + exp2 denominator (lane owns one q-row) ----
    for (int kt = 0; kt <= qb; kt++) {
        __syncthreads();
        #pragma unroll
        for (int i = 0; i < 2; i++) {
            int chunk = tid + i * 256;
            int row = chunk >> 3, cc = chunk & 7;
            v4i v = *(const v4i*)(Kq + (long)(kt * 64 + row) * KVDIM + kvh * 128 + cc * 16);
            *(v4i*)(Ks + row * 128 + ((cc ^ (row & 7)) * 16)) = v;
        }
        __syncthreads();
        v4i sf[4] = {vzero, vzero, vzero, vzero};
        #pragma unroll
        for (int ks = 0; ks < 2; ks++)
            #pragma unroll
            for (int f = 0; f < 4; f++) {
                int row = f * 16 + qlan;
                v4i bk = *(const v4i*)(Ks + row * 128 + (((ks * 4 + g) ^ (row & 7)) * 16));
                sf[f] = __builtin_amdgcn_mfma_i32_16x16x64_i8(bk, aq[ks], sf[f], 0, 0, 0);  // C[k][q]
            }
        int qthr = qb * 64 + w * 16 + qlan - kt * 64;   // >=64 for non-diagonal tiles
        int sv[16];
        #pragma unroll
        for (int f = 0; f < 4; f++)
            #pragma unroll
            for (int r = 0; r < 4; r++) {
                int kl = f * 16 + g * 4 + r;
                sv[f * 4 + r] = (kl > qthr) ? NEGS : sf[f][r];
            }
        int tm = sv[0];
        #pragma unroll
        for (int e = 1; e < 16; e++) tm = tm > sv[e] ? tm : sv[e];
        tm = max(tm, __shfl_xor(tm, 16, 64));
        tm = max(tm, __shfl_xor(tm, 32, 64));
        int mn = tm > mi ? tm : mi;
        float esc = fexp2(c2 * (float)(mi - mn));
        float es = 0.f;
        #pragma unroll
        for (int e = 0; e < 16; e++) es += fexp2(c2 * (float)(sv[e] - mn));
        es += __shfl_xor(es, 16, 64);
        es += __shfl_xor(es, 32, 64);
        l = l * esc + es;
        mi = mn;
    }
    float invl = 127.0f / l;
    // ---- pass 2: quantized probs (packed dwords), int8 PV ----
    unsigned* Ps32 = (unsigned*)Qs;        // 16 kdw x 20-dword stride per warp
    int pwr = w * 320;
    v4i of[8];
    #pragma unroll
    for (int nf = 0; nf < 8; nf++) of[nf] = vzero;
    for (int kt = 0; kt <= qb; kt++) {
        __syncthreads();
        #pragma unroll
        for (int i = 0; i < 2; i++) {
            int chunk = tid + i * 256;
            int row = chunk >> 3, cc = chunk & 7;
            v4i v = *(const v4i*)(Kq + (long)(kt * 64 + row) * KVDIM + kvh * 128 + cc * 16);
            *(v4i*)(Ks + row * 128 + ((cc ^ (row & 7)) * 16)) = v;
        }
        #pragma unroll
        for (int i = 0; i < 2; i++) {
            int chunk = tid + i * 256;
            int row = chunk >> 2, cc = chunk & 3;
            v4i v = *(const v4i*)(Vtq + (long)(kvh * 128 + row) * SEQ + kt * 64 + cc * 16);
            *(v4i*)(Vs + row * 64 + ((cc ^ (row & 3)) * 16)) = v;
        }
        __syncthreads();
        v4i sf[4] = {vzero, vzero, vzero, vzero};
        #pragma unroll
        for (int ks = 0; ks < 2; ks++)
            #pragma unroll
            for (int f = 0; f < 4; f++) {
                int row = f * 16 + qlan;
                v4i bk = *(const v4i*)(Ks + row * 128 + (((ks * 4 + g) ^ (row & 7)) * 16));
                sf[f] = __builtin_amdgcn_mfma_i32_16x16x64_i8(bk, aq[ks], sf[f], 0, 0, 0);
            }
        int qthr = qb * 64 + w * 16 + qlan - kt * 64;
        #pragma unroll
        for (int f = 0; f < 4; f++) {
            unsigned pk = 0;
            #pragma unroll
            for (int r = 0; r < 4; r++) {
                int kl = f * 16 + g * 4 + r;
                int s = (kl > qthr) ? NEGS : sf[f][r];
                float t = fexp2(c2 * (float)(s - mi));
                int pq = (int)rintf(t * invl);       // 0..127 by construction
                pk |= ((unsigned)pq) << (8 * r);
            }
            Ps32[pwr + (4 * f + g) * 20 + qlan] = pk;
        }
        // PV A-fragment: lane needs q-row = qlan, k-block = g (4 dwords, stride 20)
        int rb = pwr + 80 * g + qlan;
        v4i ap;
        ap[0] = (int)Ps32[rb];
        ap[1] = (int)Ps32[rb + 20];
        ap[2] = (int)Ps32[rb + 40];
        ap[3] = (int)Ps32[rb + 60];
        #pragma unroll
        for (int nf = 0; nf < 8; nf++) {
            int row = nf * 16 + qlan;
            v4i bv = *(const v4i*)(Vs + row * 64 + ((g ^ (row & 3)) * 16));
            of[nf] = __builtin_amdgcn_mfma_i32_16x16x64_i8(ap, bv, of[nf], 0, 0, 0);
        }
    }
    int mymax = 0;
    #pragma unroll
    for (int nf = 0; nf < 8; nf++)
        #pragma unroll
        for (int r = 0; r < 4; r++) {
            int val = of[nf][r];
            int av = val < 0 ? -val : val;
            mymax = av > mymax ? av : mymax;
            int qg = qb * 64 + w * 16 + 4 * g + r;
            AO[(long)qg * HID + h * 128 + nf * 16 + qlan] = val;
        }
    #pragma unroll
    for (int off = 1; off < 64; off <<= 1) {
        int o2 = __shfl_xor(mymax, off, 64);
        mymax = o2 > mymax ? o2 : mymax;
    }
    if (lane == 0) atomicMax(slots + 8, (unsigned)mymax);
}

// ---------------- quantize attn_out (int32 -> int8), publish absmax to slot 9 ----------------
__global__ void k_quant_ao(const int* __restrict__ a, int8_t* __restrict__ q, unsigned* slots) {
    float sv = slot_scale(slots, 7);
    float spv = (1.0f / 127.0f) * sv;
    float amax = spv * (float)(int)slots[8];
    float s = fmaxf(amax / 127.0f, 1e-8f);
    long nvec = (long)SEQ * HID / 4;
    for (long vid = blockIdx.x * (long)blockDim.x + threadIdx.x; vid < nvec;
         vid += (long)gridDim.x * blockDim.x) {
        int4 v = *(const int4*)(a + vid * 4);
        int a0 = q8v(spv * (float)v.x, s);
        int a1 = q8v(spv * (float)v.y, s);
        int a2 = q8v(spv * (float)v.z, s);
        int a3 = q8v(spv * (float)v.w, s);
        unsigned pa = (unsigned)(uint8_t)(int8_t)a0
                    | ((unsigned)(uint8_t)(int8_t)a1 << 8)
                    | ((unsigned)(uint8_t)(int8_t)a2 << 16)
                    | ((unsigned)(uint8_t)(int8_t)a3 << 24);
        *(unsigned*)(q + vid * 4) = pa;
    }
    if (blockIdx.x == 0 && threadIdx.x == 0) slots[9] = __float_as_uint(amax);
}

extern "C" void kernel_launch(void* const* d_in, const int* in_sizes, int n_in,
                              void* d_out, int out_size, void* d_ws, size_t ws_size,
                              hipStream_t stream) {
    (void)in_sizes; (void)n_in; (void)out_size;
    const float* hid = (const float*)d_in[0];
    const int* pos = (const int*)d_in[2];
    const float* wqp = (const float*)d_in[3];
    const float* wkp = (const float*)d_in[4];
    const float* wvp = (const float*)d_in[5];
    const float* wop = (const float*)d_in[6];
    float* out = (float*)d_out;
    char* ws = (char*)d_ws;

    size_t o = 0;
    auto alloc = [&](size_t sz) { size_t r = o; o += (sz + 255) & ~(size_t)255; return r; };
    unsigned* slots = (unsigned*)(ws + alloc(256));
    int8_t* Xq   = (int8_t*)(ws + alloc((size_t)SEQ * HID));      // later reused as AOq
    int8_t* Wqq  = (int8_t*)(ws + alloc((size_t)HID * HID));      // later reused as Woq
    int8_t* Wkvq = (int8_t*)(ws + alloc((size_t)KVCAT * HID));
    float*  Qf   = (float*)(ws + alloc((size_t)SEQ * HID * 4));   // later reused as AOint
    float*  KVf  = (float*)(ws + alloc((size_t)SEQ * KVCAT * 4));
    int8_t* Qq   = (int8_t*)(ws + alloc((size_t)SEQ * HID));
    int8_t* Kq   = (int8_t*)(ws + alloc((size_t)SEQ * KVDIM));
    int8_t* Vtq  = (int8_t*)(ws + alloc((size_t)KVDIM * SEQ));
    float*  ctab = (float*)(ws + alloc((size_t)SEQ * 64 * 4));
    float*  stab = (float*)(ws + alloc((size_t)SEQ * 64 * 4));
    if (ws_size < o) return;
    int8_t* Woq = Wqq;
    int*    AOint = (int*)Qf;
    int8_t* AOq = Xq;

    hipMemsetAsync(slots, 0, 256, stream);
    k_ropetab<<<SEQ * 64 / 256, 256, 0, stream>>>(pos, ctab, stab);
    k_absmax5<<<2048, 256, 0, stream>>>(hid, wqp, wkp, wvp, wop, slots);
    k_quant4<<<2048, 256, 0, stream>>>(hid, wqp, wkp, wvp,
                                       Xq, Wqq, Wkvq, Wkvq + (size_t)KVDIM * HID, slots);
    k_gemm_i8<<<512, 256, 0, stream>>>(Xq, Wqq, Qf, SEQ, HID, HID, slots,
                                       0, 1, 1, 1 << 30, -1, 1 << 30);
    k_gemm_i8<<<256, 256, 0, stream>>>(Xq, Wkvq, KVf, SEQ, KVCAT, HID, slots,
                                       0, 2, 3, KVDIM, 7, KVDIM);   // fused V absmax -> slot 7
    const long CALL = 0x3FFFFFFFL;
    k_quant<<<2048, 256, 0, stream>>>(wop, Woq, (long)HID * HID / 4, 40, CALL, 0, slots, 4);
    k_rope<<<SEQ * NH * 16 / 256, 256, 0, stream>>>(Qf, HID, 5, ctab, stab, slots, 5);
    k_rope<<<SEQ * NKV * 16 / 256, 256, 0, stream>>>(KVf, KVCAT, 3, ctab, stab, slots, 6);
    k_quant<<<2048, 256, 0, stream>>>(Qf, Qq, (long)SEQ * HID / 4, 40, CALL, 0, slots, 5);
    k_quant<<<1024, 256, 0, stream>>>(KVf, Kq, (long)SEQ * KVDIM / 4, 8, 255, KVCAT, slots, 6);
    k_transq<<<dim3(32, 64), 256, 0, stream>>>(KVf + KVDIM, KVCAT, Vtq, SEQ, slots, 7);
    k_attn<<<1024, 256, 0, stream>>>(Qq, Kq, Vtq, AOint, slots);
    k_quant_ao<<<2048, 256, 0, stream>>>(AOint, AOq, slots);
    k_gemm_i8<<<512, 256, 0, stream>>>(AOq, Woq, out, SEQ, HID, HID, slots,
                                       9, 4, 4, 1 << 30, -1, 1 << 30);
}

// Round 3
// 350.794 us; speedup vs baseline: 2.9776x; 2.9776x over previous
//
#include <hip/hip_runtime.h>
#include <stdint.h>

#define SEQ   2048
#define HID   4096
#define NH    32
#define NKV   8
#define KVDIM 1024   // NKV*HD
#define KVCAT 2048   // KVDIM*2

typedef int v4i __attribute__((ext_vector_type(4)));

// slots live 128 B apart to avoid same-line atomic serialization
__device__ __forceinline__ float slot_scale(const unsigned* slots, int slot) {
    return fmaxf(__uint_as_float(slots[slot << 5]) / 127.0f, 1e-8f);
}

__device__ __forceinline__ int q8v(float x, float s) {
    int v = (int)rintf(x / s);
    return v < -127 ? -127 : (v > 127 ? 127 : v);
}

__device__ __forceinline__ float fexp2(float x) {
    float r; asm("v_exp_f32 %0, %1" : "=v"(r) : "v"(x)); return r;
}

__device__ __forceinline__ float amax4(const float* __restrict__ p, long v) {
    float4 x = *(const float4*)(p + v * 4);
    return fmaxf(fmaxf(fabsf(x.x), fabsf(x.y)), fmaxf(fabsf(x.z), fabsf(x.w)));
}

// block-level reduce (4 waves) then ONE atomic per block
__device__ __forceinline__ void block_amax_atomic(float m, unsigned* slots, int slot) {
    __shared__ float sm[4];
    int lane = threadIdx.x & 63, w = threadIdx.x >> 6;
    for (int off = 32; off; off >>= 1) m = fmaxf(m, __shfl_xor(m, off, 64));
    if (lane == 0) sm[w] = m;
    __syncthreads();
    if (threadIdx.x == 0)
        atomicMax(slots + (slot << 5),
                  __float_as_uint(fmaxf(fmaxf(sm[0], sm[1]), fmaxf(sm[2], sm[3]))));
}

// ---------------- fused absmax: blocks partitioned per tensor ----------------
#define NV0 ((long)SEQ * HID / 4)     // 2M vecs
#define NV1 ((long)HID * HID / 4)     // 4M vecs
#define NV2 ((long)KVDIM * HID / 4)   // 1M vecs
__global__ void k_absmax5(const float* __restrict__ a0, const float* __restrict__ a1,
                          const float* __restrict__ a2, const float* __restrict__ a3,
                          const float* __restrict__ a4, unsigned* slots) {
    int b = blockIdx.x;
    const float* p; long n; int slot, lb, nb;
    if (b < 342)       { p = a0; n = NV0; slot = 0; lb = b;        nb = 342; }
    else if (b < 1025) { p = a1; n = NV1; slot = 1; lb = b - 342;  nb = 683; }
    else if (b < 1196) { p = a2; n = NV2; slot = 2; lb = b - 1025; nb = 171; }
    else if (b < 1367) { p = a3; n = NV2; slot = 3; lb = b - 1196; nb = 171; }
    else               { p = a4; n = NV1; slot = 4; lb = b - 1367; nb = 681; }
    long str = (long)nb * 256;
    float m = 0.f, m2 = 0.f;
    long v = (long)lb * 256 + threadIdx.x;
    for (; v + str < n; v += 2 * str) {
        m  = fmaxf(m,  amax4(p, v));
        m2 = fmaxf(m2, amax4(p, v + str));
    }
    if (v < n) m = fmaxf(m, amax4(p, v));
    block_amax_atomic(fmaxf(m, m2), slots, slot);
}

__device__ __forceinline__ void qstore4(const float* __restrict__ src, long v,
                                        int8_t* __restrict__ dst, float s) {
    float4 x = *(const float4*)(src + v * 4);
    unsigned pa = (unsigned)(uint8_t)(int8_t)q8v(x.x, s)
                | ((unsigned)(uint8_t)(int8_t)q8v(x.y, s) << 8)
                | ((unsigned)(uint8_t)(int8_t)q8v(x.z, s) << 16)
                | ((unsigned)(uint8_t)(int8_t)q8v(x.w, s) << 24);
    *(unsigned*)(dst + v * 4) = pa;
}

// ---------------- fused quantize of hid, wq, wk, wv (blocks partitioned) ----------------
__global__ void k_quant4(const float* __restrict__ a0, const float* __restrict__ a1,
                         const float* __restrict__ a2, const float* __restrict__ a3,
                         int8_t* __restrict__ d0, int8_t* __restrict__ d1,
                         int8_t* __restrict__ d2, int8_t* __restrict__ d3,
                         const unsigned* __restrict__ slots) {
    int b = blockIdx.x;
    const float* p; int8_t* d; long n; int slot, lb, nb;
    if (b < 512)       { p = a0; d = d0; n = NV0; slot = 0; lb = b;        nb = 512; }
    else if (b < 1536) { p = a1; d = d1; n = NV1; slot = 1; lb = b - 512;  nb = 1024; }
    else if (b < 1792) { p = a2; d = d2; n = NV2; slot = 2; lb = b - 1536; nb = 256; }
    else               { p = a3; d = d3; n = NV2; slot = 3; lb = b - 1792; nb = 256; }
    float s = slot_scale(slots, slot);
    long str = (long)nb * 256;
    for (long v = (long)lb * 256 + threadIdx.x; v < n; v += str) qstore4(p, v, d, s);
}

// ---------------- generic quantize f32 -> int8 (dst contiguous, src strided) ----------------
__global__ void k_quant(const float* __restrict__ x, int8_t* __restrict__ q, long nvec,
                        int rshift, long cmaskv, long ld,
                        const unsigned* __restrict__ slots, int slot) {
    float s = slot_scale(slots, slot);
    for (long vid = blockIdx.x * (long)blockDim.x + threadIdx.x; vid < nvec;
         vid += (long)gridDim.x * blockDim.x) {
        long r = vid >> rshift;
        long c = (vid & cmaskv) << 2;
        float4 v = *(const float4*)(x + r * ld + c);
        unsigned pa = (unsigned)(uint8_t)(int8_t)q8v(v.x, s)
                    | ((unsigned)(uint8_t)(int8_t)q8v(v.y, s) << 8)
                    | ((unsigned)(uint8_t)(int8_t)q8v(v.z, s) << 16)
                    | ((unsigned)(uint8_t)(int8_t)q8v(v.w, s) << 24);
        *(unsigned*)(q + vid * 4) = pa;
    }
}

// ---------------- rope cos/sin table ----------------
__global__ void k_ropetab(const int* __restrict__ pos, float* __restrict__ ct,
                          float* __restrict__ st) {
    int tid = blockIdx.x * blockDim.x + threadIdx.x;
    if (tid >= SEQ * 64) return;
    int i = tid & 63, s = tid >> 6;
    double inv = 1.0 / pow(10000.0, (double)((float)(2 * i) * (1.0f / 128.0f)));
    float invf = (float)inv;
    float angf = (float)pos[s] * invf;
    double a = (double)angf;
    ct[tid] = (float)cos(a);
    st[tid] = (float)sin(a);
}

// ---------------- rope in-place (float4, grid-stride) + block absmax ----------------
__global__ void k_rope(float* __restrict__ x, long ld, int hbits, int total,
                       const float* __restrict__ ct, const float* __restrict__ st,
                       unsigned* slots, int slot) {
    float m = 0.f;
    for (int t = blockIdx.x * blockDim.x + threadIdx.x; t < total;
         t += gridDim.x * blockDim.x) {
        int i4 = t & 15;
        int h = (t >> 4) & ((1 << hbits) - 1);
        int s = t >> (4 + hbits);
        long base = (long)s * ld + h * 128 + i4 * 4;
        float4 a = *(float4*)(x + base);
        float4 b = *(float4*)(x + base + 64);
        float4 c = *(const float4*)(ct + s * 64 + i4 * 4);
        float4 sn = *(const float4*)(st + s * 64 + i4 * 4);
        float4 o0, o1;
        o0.x = a.x * c.x - b.x * sn.x;  o1.x = b.x * c.x + a.x * sn.x;
        o0.y = a.y * c.y - b.y * sn.y;  o1.y = b.y * c.y + a.y * sn.y;
        o0.z = a.z * c.z - b.z * sn.z;  o1.z = b.z * c.z + a.z * sn.z;
        o0.w = a.w * c.w - b.w * sn.w;  o1.w = b.w * c.w + a.w * sn.w;
        *(float4*)(x + base) = o0;
        *(float4*)(x + base + 64) = o1;
        m = fmaxf(m,
            fmaxf(fmaxf(fmaxf(fabsf(o0.x), fabsf(o0.y)), fmaxf(fabsf(o0.z), fabsf(o0.w))),
                  fmaxf(fmaxf(fabsf(o1.x), fabsf(o1.y)), fmaxf(fabsf(o1.z), fabsf(o1.w)))));
    }
    block_amax_atomic(m, slots, slot);
}

// ---------------- transpose + quantize (V -> V^T int8) ----------------
__global__ void k_transq(const float* __restrict__ src, long lds_, int8_t* __restrict__ dst,
                         long ldd, const unsigned* __restrict__ slots, int slot) {
    __shared__ float t[32][33];
    float s = slot_scale(slots, slot);
    int bx = blockIdx.x, by = blockIdx.y;
    int tid = threadIdx.x;
    int c = tid & 31, r0 = tid >> 5;
    #pragma unroll
    for (int j = 0; j < 4; j++) {
        int r = r0 + j * 8;
        t[r][c] = src[(long)(by * 32 + r) * lds_ + bx * 32 + c];
    }
    __syncthreads();
    int d = tid >> 3, k4 = (tid & 7) * 4;
    unsigned pa = 0;
    #pragma unroll
    for (int j = 0; j < 4; j++) {
        int iv = q8v(t[k4 + j][d], s);
        pa |= ((unsigned)(uint8_t)(int8_t)iv) << (8 * j);
    }
    *(unsigned*)(dst + (long)(bx * 32 + d) * ldd + by * 32 + k4) = pa;
}

// ---------------- int8 GEMM: C[M][N] = sA*sB * (A[M][K] . B[N][K]^T) ----------------
__global__ __launch_bounds__(256) void k_gemm_i8(
    const int8_t* __restrict__ A, const int8_t* __restrict__ B, float* __restrict__ C,
    int M, int N, int K, unsigned* slots,
    int slotA, int slotB, int slotB2, int nsplit, int am_slot, int am_col0) {
    __shared__ int8_t As[128 * 128];
    __shared__ int8_t Bs[128 * 128];
    const v4i vzero = {0, 0, 0, 0};
    int tid = threadIdx.x, lane = tid & 63, wid = tid >> 6;
    int nbx = N >> 7;
    int nwg = gridDim.x, wg = blockIdx.x;
    int cpx = nwg >> 3;
    int swz = (wg & 7) * cpx + (wg >> 3);
    int bm = swz / nbx, bn = swz % nbx;
    long rowA0 = (long)bm * 128, colB0 = (long)bn * 128;
    int wrow = (wid >> 1) * 64, wcol = (wid & 1) * 64;
    v4i acc[4][4];
    #pragma unroll
    for (int m = 0; m < 4; m++)
        #pragma unroll
        for (int n = 0; n < 4; n++) acc[m][n] = vzero;
    for (int kt = 0; kt < K; kt += 128) {
        #pragma unroll
        for (int i = 0; i < 4; i++) {
            int chunk = tid + i * 256;
            int row = chunk >> 3, cc = chunk & 7;
            int sw = (cc ^ (row & 7)) * 16;
            v4i av = *(const v4i*)(A + (rowA0 + row) * K + kt + cc * 16);
            v4i bv = *(const v4i*)(B + (colB0 + row) * K + kt + cc * 16);
            *(v4i*)(As + row * 128 + sw) = av;
            *(v4i*)(Bs + row * 128 + sw) = bv;
        }
        __syncthreads();
        #pragma unroll
        for (int ks = 0; ks < 2; ks++) {
            v4i af[4], bf[4];
            #pragma unroll
            for (int m = 0; m < 4; m++) {
                int row = wrow + m * 16 + (lane & 15);
                af[m] = *(const v4i*)(As + row * 128 + (((ks * 4 + (lane >> 4)) ^ (row & 7)) * 16));
            }
            #pragma unroll
            for (int n = 0; n < 4; n++) {
                int row = wcol + n * 16 + (lane & 15);
                bf[n] = *(const v4i*)(Bs + row * 128 + (((ks * 4 + (lane >> 4)) ^ (row & 7)) * 16));
            }
            #pragma unroll
            for (int m = 0; m < 4; m++)
                #pragma unroll
                for (int n = 0; n < 4; n++)
                    acc[m][n] = __builtin_amdgcn_mfma_i32_16x16x64_i8(af[m], bf[n], acc[m][n], 0, 0, 0);
        }
        __syncthreads();
    }
    float sA = slot_scale(slots, slotA);
    float sB1 = slot_scale(slots, slotB);
    float sB2 = slot_scale(slots, slotB2);
    float am = 0.f;
    #pragma unroll
    for (int m = 0; m < 4; m++) {
        long row0 = rowA0 + wrow + m * 16 + ((lane >> 4) << 2);
        #pragma unroll
        for (int n = 0; n < 4; n++) {
            int col = (int)colB0 + wcol + n * 16 + (lane & 15);
            float sc = sA * ((col < nsplit) ? sB1 : sB2);
            float* cp = C + row0 * N + col;
            #pragma unroll
            for (int r = 0; r < 4; r++) {
                float val = sc * (float)acc[m][n][r];
                cp[(long)r * N] = val;
                if (col >= am_col0) am = fmaxf(am, fabsf(val));
            }
        }
    }
    if (am_slot >= 0) block_amax_atomic(am, slots, am_slot);
}

// ---------------- two-pass flash attention (int8, swapped QK^T, exp2-fast) ----------------
__global__ __launch_bounds__(256) void k_attn(
    const int8_t* __restrict__ Qq, const int8_t* __restrict__ Kq, const int8_t* __restrict__ Vtq,
    int* __restrict__ AO, unsigned* slots) {
    __shared__ int8_t Qs[64 * 128];   // reused as packed-P store in pass 2
    __shared__ int8_t Ks[64 * 128];
    __shared__ int8_t Vs[128 * 64];
    __shared__ int smx[4];
    const v4i vzero = {0, 0, 0, 0};
    const int NEGS = -(1 << 29);
    int tid = threadIdx.x, lane = tid & 63, w = tid >> 6;
    int qlan = lane & 15, g = lane >> 4;
    int idx = blockIdx.x;
    int qb = 31 - (idx >> 5), h = idx & 31, kvh = h >> 2;   // long blocks first
    float sq = slot_scale(slots, 5), sk = slot_scale(slots, 6);
    float c2 = sq * sk * 0.08838834764831845f * 1.4426950408889634f;  // /sqrt(128)*log2(e)
    #pragma unroll
    for (int i = 0; i < 2; i++) {
        int chunk = tid + i * 256;
        int row = chunk >> 3, cc = chunk & 7;
        v4i v = *(const v4i*)(Qq + (long)(qb * 64 + row) * HID + h * 128 + cc * 16);
        *(v4i*)(Qs + row * 128 + ((cc ^ (row & 7)) * 16)) = v;
    }
    __syncthreads();
    v4i aq[2];
    #pragma unroll
    for (int ks = 0; ks < 2; ks++) {
        int row = w * 16 + qlan;
        aq[ks] = *(const v4i*)(Qs + row * 128 + (((ks * 4 + g) ^ (row & 7)) * 16));
    }
    int mi = -(1 << 30);
    float l = 0.f;
    // ---- pass 1: int row-max + exp2 denominator (lane owns one q-row) ----
    for (int kt = 0; kt <= qb; kt++) {
        __syncthreads();
        #pragma unroll
        for (int i = 0; i < 2; i++) {
            int chunk = tid + i * 256;
            int row = chunk >> 3, cc = chunk & 7;
            v4i v = *(const v4i*)(Kq + (long)(kt * 64 + row) * KVDIM + kvh * 128 + cc * 16);
            *(v4i*)(Ks + row * 128 + ((cc ^ (row & 7)) * 16)) = v;
        }
        __syncthreads();
        v4i sf[4] = {vzero, vzero, vzero, vzero};
        #pragma unroll
        for (int ks = 0; ks < 2; ks++)
            #pragma unroll
            for (int f = 0; f < 4; f++) {
                int row = f * 16 + qlan;
                v4i bk = *(const v4i*)(Ks + row * 128 + (((ks * 4 + g) ^ (row & 7)) * 16));
                sf[f] = __builtin_amdgcn_mfma_i32_16x16x64_i8(bk, aq[ks], sf[f], 0, 0, 0);  // C[k][q]
            }
        int qthr = qb * 64 + w * 16 + qlan - kt * 64;
        int sv[16];
        #pragma unroll
        for (int f = 0; f < 4; f++)
            #pragma unroll
            for (int r = 0; r < 4; r++) {
                int kl = f * 16 + g * 4 + r;
                sv[f * 4 + r] = (kl > qthr) ? NEGS : sf[f][r];
            }
        int tm = sv[0];
        #pragma unroll
        for (int e = 1; e < 16; e++) tm = tm > sv[e] ? tm : sv[e];
        tm = max(tm, __shfl_xor(tm, 16, 64));
        tm = max(tm, __shfl_xor(tm, 32, 64));
        int mn = tm > mi ? tm : mi;
        float esc = fexp2(c2 * (float)(mi - mn));
        float es = 0.f;
        #pragma unroll
        for (int e = 0; e < 16; e++) es += fexp2(c2 * (float)(sv[e] - mn));
        es += __shfl_xor(es, 16, 64);
        es += __shfl_xor(es, 32, 64);
        l = l * esc + es;
        mi = mn;
    }
    float invl = 127.0f / l;
    // ---- pass 2: quantized probs (packed dwords), int8 PV ----
    unsigned* Ps32 = (unsigned*)Qs;        // 16 kdw x 20-dword stride per warp
    int pwr = w * 320;
    v4i of[8];
    #pragma unroll
    for (int nf = 0; nf < 8; nf++) of[nf] = vzero;
    for (int kt = 0; kt <= qb; kt++) {
        __syncthreads();
        #pragma unroll
        for (int i = 0; i < 2; i++) {
            int chunk = tid + i * 256;
            int row = chunk >> 3, cc = chunk & 7;
            v4i v = *(const v4i*)(Kq + (long)(kt * 64 + row) * KVDIM + kvh * 128 + cc * 16);
            *(v4i*)(Ks + row * 128 + ((cc ^ (row & 7)) * 16)) = v;
        }
        #pragma unroll
        for (int i = 0; i < 2; i++) {
            int chunk = tid + i * 256;
            int row = chunk >> 2, cc = chunk & 3;
            v4i v = *(const v4i*)(Vtq + (long)(kvh * 128 + row) * SEQ + kt * 64 + cc * 16);
            *(v4i*)(Vs + row * 64 + ((cc ^ (row & 3)) * 16)) = v;
        }
        __syncthreads();
        v4i sf[4] = {vzero, vzero, vzero, vzero};
        #pragma unroll
        for (int ks = 0; ks < 2; ks++)
            #pragma unroll
            for (int f = 0; f < 4; f++) {
                int row = f * 16 + qlan;
                v4i bk = *(const v4i*)(Ks + row * 128 + (((ks * 4 + g) ^ (row & 7)) * 16));
                sf[f] = __builtin_amdgcn_mfma_i32_16x16x64_i8(bk, aq[ks], sf[f], 0, 0, 0);
            }
        int qthr = qb * 64 + w * 16 + qlan - kt * 64;
        #pragma unroll
        for (int f = 0; f < 4; f++) {
            unsigned pk = 0;
            #pragma unroll
            for (int r = 0; r < 4; r++) {
                int kl = f * 16 + g * 4 + r;
                int s = (kl > qthr) ? NEGS : sf[f][r];
                float t = fexp2(c2 * (float)(s - mi));
                int pq = (int)rintf(t * invl);
                pk |= ((unsigned)pq) << (8 * r);
            }
            Ps32[pwr + (4 * f + g) * 20 + qlan] = pk;
        }
        int rb = pwr + 80 * g + qlan;
        v4i ap;
        ap[0] = (int)Ps32[rb];
        ap[1] = (int)Ps32[rb + 20];
        ap[2] = (int)Ps32[rb + 40];
        ap[3] = (int)Ps32[rb + 60];
        #pragma unroll
        for (int nf = 0; nf < 8; nf++) {
            int row = nf * 16 + qlan;
            v4i bv = *(const v4i*)(Vs + row * 64 + ((g ^ (row & 3)) * 16));
            of[nf] = __builtin_amdgcn_mfma_i32_16x16x64_i8(ap, bv, of[nf], 0, 0, 0);
        }
    }
    int mymax = 0;
    #pragma unroll
    for (int nf = 0; nf < 8; nf++)
        #pragma unroll
        for (int r = 0; r < 4; r++) {
            int val = of[nf][r];
            int av = val < 0 ? -val : val;
            mymax = av > mymax ? av : mymax;
            int qg = qb * 64 + w * 16 + 4 * g + r;
            AO[(long)qg * HID + h * 128 + nf * 16 + qlan] = val;
        }
    #pragma unroll
    for (int off = 1; off < 64; off <<= 1) {
        int o2 = __shfl_xor(mymax, off, 64);
        mymax = o2 > mymax ? o2 : mymax;
    }
    if (lane == 0) smx[w] = mymax;
    __syncthreads();
    if (tid == 0) {
        int mm = max(max(smx[0], smx[1]), max(smx[2], smx[3]));
        atomicMax(slots + (8 << 5), (unsigned)mm);
    }
}

// ---------------- quantize attn_out (int32 -> int8), publish absmax to slot 9 ----------------
__global__ void k_quant_ao(const int* __restrict__ a, int8_t* __restrict__ q, unsigned* slots) {
    float sv = slot_scale(slots, 7);
    float spv = (1.0f / 127.0f) * sv;
    float amax = spv * (float)(int)slots[8 << 5];
    float s = fmaxf(amax / 127.0f, 1e-8f);
    long nvec = (long)SEQ * HID / 4;
    for (long vid = blockIdx.x * (long)blockDim.x + threadIdx.x; vid < nvec;
         vid += (long)gridDim.x * blockDim.x) {
        int4 v = *(const int4*)(a + vid * 4);
        int a0 = q8v(spv * (float)v.x, s);
        int a1 = q8v(spv * (float)v.y, s);
        int a2 = q8v(spv * (float)v.z, s);
        int a3 = q8v(spv * (float)v.w, s);
        unsigned pa = (unsigned)(uint8_t)(int8_t)a0
                    | ((unsigned)(uint8_t)(int8_t)a1 << 8)
                    | ((unsigned)(uint8_t)(int8_t)a2 << 16)
                    | ((unsigned)(uint8_t)(int8_t)a3 << 24);
        *(unsigned*)(q + vid * 4) = pa;
    }
    if (blockIdx.x == 0 && threadIdx.x == 0) slots[9 << 5] = __float_as_uint(amax);
}

extern "C" void kernel_launch(void* const* d_in, const int* in_sizes, int n_in,
                              void* d_out, int out_size, void* d_ws, size_t ws_size,
                              hipStream_t stream) {
    (void)in_sizes; (void)n_in; (void)out_size;
    const float* hid = (const float*)d_in[0];
    const int* pos = (const int*)d_in[2];
    const float* wqp = (const float*)d_in[3];
    const float* wkp = (const float*)d_in[4];
    const float* wvp = (const float*)d_in[5];
    const float* wop = (const float*)d_in[6];
    float* out = (float*)d_out;
    char* ws = (char*)d_ws;

    size_t o = 0;
    auto alloc = [&](size_t sz) { size_t r = o; o += (sz + 255) & ~(size_t)255; return r; };
    unsigned* slots = (unsigned*)(ws + alloc(2048));
    int8_t* Xq   = (int8_t*)(ws + alloc((size_t)SEQ * HID));      // later reused as AOq
    int8_t* Wqq  = (int8_t*)(ws + alloc((size_t)HID * HID));      // later reused as Woq
    int8_t* Wkvq = (int8_t*)(ws + alloc((size_t)KVCAT * HID));
    float*  Qf   = (float*)(ws + alloc((size_t)SEQ * HID * 4));   // later reused as AOint
    float*  KVf  = (float*)(ws + alloc((size_t)SEQ * KVCAT * 4));
    int8_t* Qq   = (int8_t*)(ws + alloc((size_t)SEQ * HID));
    int8_t* Kq   = (int8_t*)(ws + alloc((size_t)SEQ * KVDIM));
    int8_t* Vtq  = (int8_t*)(ws + alloc((size_t)KVDIM * SEQ));
    float*  ctab = (float*)(ws + alloc((size_t)SEQ * 64 * 4));
    float*  stab = (float*)(ws + alloc((size_t)SEQ * 64 * 4));
    if (ws_size < o) return;
    int8_t* Woq = Wqq;
    int*    AOint = (int*)Qf;
    int8_t* AOq = Xq;

    hipMemsetAsync(slots, 0, 2048, stream);
    k_ropetab<<<SEQ * 64 / 256, 256, 0, stream>>>(pos, ctab, stab);
    k_absmax5<<<2048, 256, 0, stream>>>(hid, wqp, wkp, wvp, wop, slots);
    k_quant4<<<2048, 256, 0, stream>>>(hid, wqp, wkp, wvp,
                                       Xq, Wqq, Wkvq, Wkvq + (size_t)KVDIM * HID, slots);
    k_gemm_i8<<<512, 256, 0, stream>>>(Xq, Wqq, Qf, SEQ, HID, HID, slots,
                                       0, 1, 1, 1 << 30, -1, 1 << 30);
    k_gemm_i8<<<256, 256, 0, stream>>>(Xq, Wkvq, KVf, SEQ, KVCAT, HID, slots,
                                       0, 2, 3, KVDIM, 7, KVDIM);   // fused V absmax -> slot 7
    const long CALL = 0x3FFFFFFFL;
    k_quant<<<2048, 256, 0, stream>>>(wop, Woq, (long)HID * HID / 4, 40, CALL, 0, slots, 4);
    k_rope<<<1024, 256, 0, stream>>>(Qf, HID, 5, SEQ * NH * 16, ctab, stab, slots, 5);
    k_rope<<<1024, 256, 0, stream>>>(KVf, KVCAT, 3, SEQ * NKV * 16, ctab, stab, slots, 6);
    k_quant<<<2048, 256, 0, stream>>>(Qf, Qq, (long)SEQ * HID / 4, 40, CALL, 0, slots, 5);
    k_quant<<<1024, 256, 0, stream>>>(KVf, Kq, (long)SEQ * KVDIM / 4, 8, 255, KVCAT, slots, 6);
    k_transq<<<dim3(32, 64), 256, 0, stream>>>(KVf + KVDIM, KVCAT, Vtq, SEQ, slots, 7);
    k_attn<<<1024, 256, 0, stream>>>(Qq, Kq, Vtq, AOint, slots);
    k_quant_ao<<<2048, 256, 0, stream>>>(AOint, AOq, slots);
    k_gemm_i8<<<512, 256, 0, stream>>>(AOq, Woq, out, SEQ, HID, HID, slots,
                                       9, 4, 4, 1 << 30, -1, 1 << 30);
}

// Round 4
// 319.118 us; speedup vs baseline: 3.2731x; 1.0993x over previous
//
#include <hip/hip_runtime.h>
#include <stdint.h>

#define SEQ   2048
#define HID   4096
#define NH    32
#define NKV   8
#define KVDIM 1024   // NKV*HD
#define KVCAT 2048   // KVDIM*2

typedef int v4i __attribute__((ext_vector_type(4)));

#define VMCNT0 asm volatile("s_waitcnt vmcnt(0)" ::: "memory")

// async global->LDS 16B: per-lane global source, wave-uniform LDS base + lane*16
__device__ __forceinline__ void gload16(const void* g, void* l) {
    __builtin_amdgcn_global_load_lds(
        (const __attribute__((address_space(1))) void*)(uintptr_t)g,
        (__attribute__((address_space(3))) void*)(uintptr_t)l, 16, 0, 0);
}

// slots live 128 B apart to avoid same-line atomic serialization
__device__ __forceinline__ float slot_scale(const unsigned* slots, int slot) {
    return fmaxf(__uint_as_float(slots[slot << 5]) / 127.0f, 1e-8f);
}

__device__ __forceinline__ int q8v(float x, float s) {
    int v = (int)rintf(x / s);
    return v < -127 ? -127 : (v > 127 ? 127 : v);
}

__device__ __forceinline__ float fexp2(float x) {
    float r; asm("v_exp_f32 %0, %1" : "=v"(r) : "v"(x)); return r;
}

__device__ __forceinline__ float amax4(const float* __restrict__ p, long v) {
    float4 x = *(const float4*)(p + v * 4);
    return fmaxf(fmaxf(fabsf(x.x), fabsf(x.y)), fmaxf(fabsf(x.z), fabsf(x.w)));
}

// block-level reduce (4 waves) then ONE atomic per block
__device__ __forceinline__ void block_amax_atomic(float m, unsigned* slots, int slot) {
    __shared__ float sm[4];
    int lane = threadIdx.x & 63, w = threadIdx.x >> 6;
    for (int off = 32; off; off >>= 1) m = fmaxf(m, __shfl_xor(m, off, 64));
    if (lane == 0) sm[w] = m;
    __syncthreads();
    if (threadIdx.x == 0)
        atomicMax(slots + (slot << 5),
                  __float_as_uint(fmaxf(fmaxf(sm[0], sm[1]), fmaxf(sm[2], sm[3]))));
}

// ---------------- fused absmax: blocks partitioned per tensor ----------------
#define NV0 ((long)SEQ * HID / 4)     // 2M vecs
#define NV1 ((long)HID * HID / 4)     // 4M vecs
#define NV2 ((long)KVDIM * HID / 4)   // 1M vecs
__global__ void k_absmax5(const float* __restrict__ a0, const float* __restrict__ a1,
                          const float* __restrict__ a2, const float* __restrict__ a3,
                          const float* __restrict__ a4, unsigned* slots) {
    int b = blockIdx.x;
    const float* p; long n; int slot, lb, nb;
    if (b < 342)       { p = a0; n = NV0; slot = 0; lb = b;        nb = 342; }
    else if (b < 1025) { p = a1; n = NV1; slot = 1; lb = b - 342;  nb = 683; }
    else if (b < 1196) { p = a2; n = NV2; slot = 2; lb = b - 1025; nb = 171; }
    else if (b < 1367) { p = a3; n = NV2; slot = 3; lb = b - 1196; nb = 171; }
    else               { p = a4; n = NV1; slot = 4; lb = b - 1367; nb = 681; }
    long str = (long)nb * 256;
    float m = 0.f, m2 = 0.f;
    long v = (long)lb * 256 + threadIdx.x;
    for (; v + str < n; v += 2 * str) {
        m  = fmaxf(m,  amax4(p, v));
        m2 = fmaxf(m2, amax4(p, v + str));
    }
    if (v < n) m = fmaxf(m, amax4(p, v));
    block_amax_atomic(fmaxf(m, m2), slots, slot);
}

__device__ __forceinline__ void qstore4(const float* __restrict__ src, long v,
                                        int8_t* __restrict__ dst, float s) {
    float4 x = *(const float4*)(src + v * 4);
    unsigned pa = (unsigned)(uint8_t)(int8_t)q8v(x.x, s)
                | ((unsigned)(uint8_t)(int8_t)q8v(x.y, s) << 8)
                | ((unsigned)(uint8_t)(int8_t)q8v(x.z, s) << 16)
                | ((unsigned)(uint8_t)(int8_t)q8v(x.w, s) << 24);
    *(unsigned*)(dst + v * 4) = pa;
}

// ---------------- fused quantize of hid, wq, wk, wv (blocks partitioned) ----------------
__global__ void k_quant4(const float* __restrict__ a0, const float* __restrict__ a1,
                         const float* __restrict__ a2, const float* __restrict__ a3,
                         int8_t* __restrict__ d0, int8_t* __restrict__ d1,
                         int8_t* __restrict__ d2, int8_t* __restrict__ d3,
                         const unsigned* __restrict__ slots) {
    int b = blockIdx.x;
    const float* p; int8_t* d; long n; int slot, lb, nb;
    if (b < 512)       { p = a0; d = d0; n = NV0; slot = 0; lb = b;        nb = 512; }
    else if (b < 1536) { p = a1; d = d1; n = NV1; slot = 1; lb = b - 512;  nb = 1024; }
    else if (b < 1792) { p = a2; d = d2; n = NV2; slot = 2; lb = b - 1536; nb = 256; }
    else               { p = a3; d = d3; n = NV2; slot = 3; lb = b - 1792; nb = 256; }
    float s = slot_scale(slots, slot);
    long str = (long)nb * 256;
    for (long v = (long)lb * 256 + threadIdx.x; v < n; v += str) qstore4(p, v, d, s);
}

// ---------------- generic quantize f32 -> int8 (dst contiguous, src strided) ----------------
__global__ void k_quant(const float* __restrict__ x, int8_t* __restrict__ q, long nvec,
                        int rshift, long cmaskv, long ld,
                        const unsigned* __restrict__ slots, int slot) {
    float s = slot_scale(slots, slot);
    for (long vid = blockIdx.x * (long)blockDim.x + threadIdx.x; vid < nvec;
         vid += (long)gridDim.x * blockDim.x) {
        long r = vid >> rshift;
        long c = (vid & cmaskv) << 2;
        float4 v = *(const float4*)(x + r * ld + c);
        unsigned pa = (unsigned)(uint8_t)(int8_t)q8v(v.x, s)
                    | ((unsigned)(uint8_t)(int8_t)q8v(v.y, s) << 8)
                    | ((unsigned)(uint8_t)(int8_t)q8v(v.z, s) << 16)
                    | ((unsigned)(uint8_t)(int8_t)q8v(v.w, s) << 24);
        *(unsigned*)(q + vid * 4) = pa;
    }
}

// ---------------- rope cos/sin table ----------------
__global__ void k_ropetab(const int* __restrict__ pos, float* __restrict__ ct,
                          float* __restrict__ st) {
    int tid = blockIdx.x * blockDim.x + threadIdx.x;
    if (tid >= SEQ * 64) return;
    int i = tid & 63, s = tid >> 6;
    double inv = 1.0 / pow(10000.0, (double)((float)(2 * i) * (1.0f / 128.0f)));
    float invf = (float)inv;
    float angf = (float)pos[s] * invf;
    double a = (double)angf;
    ct[tid] = (float)cos(a);
    st[tid] = (float)sin(a);
}

// ---------------- rope in-place (float4, grid-stride) + block absmax ----------------
__global__ void k_rope(float* __restrict__ x, long ld, int hbits, int total,
                       const float* __restrict__ ct, const float* __restrict__ st,
                       unsigned* slots, int slot) {
    float m = 0.f;
    for (int t = blockIdx.x * blockDim.x + threadIdx.x; t < total;
         t += gridDim.x * blockDim.x) {
        int i4 = t & 15;
        int h = (t >> 4) & ((1 << hbits) - 1);
        int s = t >> (4 + hbits);
        long base = (long)s * ld + h * 128 + i4 * 4;
        float4 a = *(float4*)(x + base);
        float4 b = *(float4*)(x + base + 64);
        float4 c = *(const float4*)(ct + s * 64 + i4 * 4);
        float4 sn = *(const float4*)(st + s * 64 + i4 * 4);
        float4 o0, o1;
        o0.x = a.x * c.x - b.x * sn.x;  o1.x = b.x * c.x + a.x * sn.x;
        o0.y = a.y * c.y - b.y * sn.y;  o1.y = b.y * c.y + a.y * sn.y;
        o0.z = a.z * c.z - b.z * sn.z;  o1.z = b.z * c.z + a.z * sn.z;
        o0.w = a.w * c.w - b.w * sn.w;  o1.w = b.w * c.w + a.w * sn.w;
        *(float4*)(x + base) = o0;
        *(float4*)(x + base + 64) = o1;
        m = fmaxf(m,
            fmaxf(fmaxf(fmaxf(fabsf(o0.x), fabsf(o0.y)), fmaxf(fabsf(o0.z), fabsf(o0.w))),
                  fmaxf(fmaxf(fabsf(o1.x), fabsf(o1.y)), fmaxf(fabsf(o1.z), fabsf(o1.w)))));
    }
    block_amax_atomic(m, slots, slot);
}

// ---------------- transpose + quantize (V -> V^T int8) ----------------
__global__ void k_transq(const float* __restrict__ src, long lds_, int8_t* __restrict__ dst,
                         long ldd, const unsigned* __restrict__ slots, int slot) {
    __shared__ float t[32][33];
    float s = slot_scale(slots, slot);
    int bx = blockIdx.x, by = blockIdx.y;
    int tid = threadIdx.x;
    int c = tid & 31, r0 = tid >> 5;
    #pragma unroll
    for (int j = 0; j < 4; j++) {
        int r = r0 + j * 8;
        t[r][c] = src[(long)(by * 32 + r) * lds_ + bx * 32 + c];
    }
    __syncthreads();
    int d = tid >> 3, k4 = (tid & 7) * 4;
    unsigned pa = 0;
    #pragma unroll
    for (int j = 0; j < 4; j++) {
        int iv = q8v(t[k4 + j][d], s);
        pa |= ((unsigned)(uint8_t)(int8_t)iv) << (8 * j);
    }
    *(unsigned*)(dst + (long)(bx * 32 + d) * ldd + by * 32 + k4) = pa;
}

// ---------------- int8 GEMM, gload_lds staging + double-buffered 2-phase ----------------
// C[M][N] = sA*sB * (A[M][K] . B[N][K]^T); LDS[row][c] = global[row][c ^ (row&7)] (16B units)
__global__ __launch_bounds__(256) void k_gemm_i8(
    const int8_t* __restrict__ A, const int8_t* __restrict__ B, float* __restrict__ C,
    int M, int N, int K, unsigned* slots,
    int slotA, int slotB, int slotB2, int nsplit, int am_slot, int am_col0) {
    __shared__ int8_t As[2][128 * 128];
    __shared__ int8_t Bs[2][128 * 128];
    const v4i vzero = {0, 0, 0, 0};
    int tid = threadIdx.x, lane = tid & 63, wid = tid >> 6;
    int nbx = N >> 7;
    int nwg = gridDim.x, wg = blockIdx.x;
    int cpx = nwg >> 3;
    int swz = (wg & 7) * cpx + (wg >> 3);
    int bm = swz / nbx, bn = swz % nbx;
    long rowA0 = (long)bm * 128, colB0 = (long)bn * 128;
    int wrow = (wid >> 1) * 64, wcol = (wid & 1) * 64;
    // staging: per-lane pre-swizzled global source, linear LDS dest
    int lr = lane >> 3;
    int swc = ((lane & 7) ^ lr) * 16;
    const int8_t* ga = A + (rowA0 + wid * 8 + lr) * (long)K + swc;
    const int8_t* gb = B + (colB0 + wid * 8 + lr) * (long)K + swc;
    v4i acc[4][4];
    #pragma unroll
    for (int m = 0; m < 4; m++)
        #pragma unroll
        for (int n = 0; n < 4; n++) acc[m][n] = vzero;

    auto STAGE = [&](int buf, int kt) {
        #pragma unroll
        for (int i = 0; i < 4; i++) {
            gload16(ga + kt + (long)(i * 32) * K, &As[buf][(wid * 8 + i * 32) * 128]);
            gload16(gb + kt + (long)(i * 32) * K, &Bs[buf][(wid * 8 + i * 32) * 128]);
        }
    };
    auto COMPUTE = [&](int buf) {
        #pragma unroll
        for (int ks = 0; ks < 2; ks++) {
            v4i af[4], bf[4];
            #pragma unroll
            for (int m = 0; m < 4; m++) {
                int row = wrow + m * 16 + (lane & 15);
                af[m] = *(const v4i*)(&As[buf][row * 128 + (((ks * 4 + (lane >> 4)) ^ (row & 7)) * 16)]);
            }
            #pragma unroll
            for (int n = 0; n < 4; n++) {
                int row = wcol + n * 16 + (lane & 15);
                bf[n] = *(const v4i*)(&Bs[buf][row * 128 + (((ks * 4 + (lane >> 4)) ^ (row & 7)) * 16)]);
            }
            #pragma unroll
            for (int m = 0; m < 4; m++)
                #pragma unroll
                for (int n = 0; n < 4; n++)
                    acc[m][n] = __builtin_amdgcn_mfma_i32_16x16x64_i8(af[m], bf[n], acc[m][n], 0, 0, 0);
        }
    };

    STAGE(0, 0);
    VMCNT0;
    __syncthreads();
    int nt = K >> 7, cur = 0;
    for (int t = 0; t < nt - 1; t++) {
        STAGE(cur ^ 1, (t + 1) << 7);
        COMPUTE(cur);
        VMCNT0;
        __syncthreads();
        cur ^= 1;
    }
    COMPUTE(cur);

    float sA = slot_scale(slots, slotA);
    float sB1 = slot_scale(slots, slotB);
    float sB2 = slot_scale(slots, slotB2);
    float am = 0.f;
    #pragma unroll
    for (int m = 0; m < 4; m++) {
        long row0 = rowA0 + wrow + m * 16 + ((lane >> 4) << 2);
        #pragma unroll
        for (int n = 0; n < 4; n++) {
            int col = (int)colB0 + wcol + n * 16 + (lane & 15);
            float sc = sA * ((col < nsplit) ? sB1 : sB2);
            float* cp = C + row0 * N + col;
            #pragma unroll
            for (int r = 0; r < 4; r++) {
                float val = sc * (float)acc[m][n][r];
                cp[(long)r * N] = val;
                if (col >= am_col0) am = fmaxf(am, fabsf(val));
            }
        }
    }
    if (am_slot >= 0) block_amax_atomic(am, slots, am_slot);
}

// ---------------- two-pass flash attention: gload_lds + K/V dbuf + mask-split ----------------
__global__ __launch_bounds__(256) void k_attn(
    const int8_t* __restrict__ Qq, const int8_t* __restrict__ Kq, const int8_t* __restrict__ Vtq,
    int* __restrict__ AO, unsigned* slots) {
    __shared__ int8_t Qs[64 * 128];   // reused as packed-P store in pass 2
    __shared__ int8_t Ks[2][64 * 128];
    __shared__ int8_t Vs[2][128 * 64];
    __shared__ int smx[4];
    const v4i vzero = {0, 0, 0, 0};
    const int NEGS = -(1 << 29);
    int tid = threadIdx.x, lane = tid & 63, w = tid >> 6;
    int qlan = lane & 15, g = lane >> 4;
    int idx = blockIdx.x;
    int qb = 31 - (idx >> 5), h = idx & 31, kvh = h >> 2;   // long blocks first
    float sq = slot_scale(slots, 5), sk = slot_scale(slots, 6);
    float c2 = sq * sk * 0.08838834764831845f * 1.4426950408889634f;  // /sqrt(128)*log2(e)
    int lr8 = lane >> 3;
    int swc = ((lane & 7) ^ lr8) * 16;
    int lr4 = lane >> 2;
    int vswc = ((lane & 3) ^ (lr4 & 3)) * 16;
    const int8_t* kbase = Kq + ((long)(w * 8 + lr8)) * KVDIM + kvh * 128 + swc;
    const int8_t* vbase = Vtq + ((long)kvh * 128 + w * 16 + lr4) * SEQ + vswc;
    auto STAGE_K = [&](int buf, int kt) {
        #pragma unroll
        for (int i = 0; i < 2; i++)
            gload16(kbase + ((long)kt * 64 + i * 32) * KVDIM, &Ks[buf][(w * 8 + i * 32) * 128]);
    };
    auto STAGE_V = [&](int buf, int kt) {
        #pragma unroll
        for (int i = 0; i < 2; i++)
            gload16(vbase + (long)(i * 64) * SEQ + kt * 64, &Vs[buf][(w * 16 + i * 64) * 64]);
    };
    // stage Q + K0
    {
        const int8_t* qbase = Qq + ((long)qb * 64 + w * 8 + lr8) * HID + h * 128 + swc;
        #pragma unroll
        for (int i = 0; i < 2; i++)
            gload16(qbase + (long)(i * 32) * HID, &Qs[(w * 8 + i * 32) * 128]);
    }
    STAGE_K(0, 0);
    VMCNT0;
    __syncthreads();
    v4i aq[2];
    #pragma unroll
    for (int ks = 0; ks < 2; ks++) {
        int row = w * 16 + qlan;
        aq[ks] = *(const v4i*)(&Qs[row * 128 + (((ks * 4 + g) ^ (row & 7)) * 16)]);
    }
    int mi = -(1 << 30);
    float l = 0.f;
    int buf = 0;
    // ---- pass 1: int row-max + exp2 denominator (lane owns one q-row) ----
    for (int kt = 0; kt <= qb; kt++) {
        if (kt < qb) STAGE_K(buf ^ 1, kt + 1);
        v4i sf[4] = {vzero, vzero, vzero, vzero};
        __builtin_amdgcn_s_setprio(1);
        #pragma unroll
        for (int ks = 0; ks < 2; ks++)
            #pragma unroll
            for (int f = 0; f < 4; f++) {
                int row = f * 16 + qlan;
                v4i bk = *(const v4i*)(&Ks[buf][row * 128 + (((ks * 4 + g) ^ (row & 7)) * 16)]);
                sf[f] = __builtin_amdgcn_mfma_i32_16x16x64_i8(bk, aq[ks], sf[f], 0, 0, 0);  // C[k][q]
            }
        __builtin_amdgcn_s_setprio(0);
        int sv[16];
        if (kt == qb) {   // only the diagonal tile masks
            int qthr = w * 16 + qlan;
            #pragma unroll
            for (int f = 0; f < 4; f++)
                #pragma unroll
                for (int r = 0; r < 4; r++) {
                    int kl = f * 16 + g * 4 + r;
                    sv[f * 4 + r] = (kl > qthr) ? NEGS : sf[f][r];
                }
        } else {
            #pragma unroll
            for (int f = 0; f < 4; f++)
                #pragma unroll
                for (int r = 0; r < 4; r++) sv[f * 4 + r] = sf[f][r];
        }
        int tm = sv[0];
        #pragma unroll
        for (int e = 1; e < 16; e++) tm = tm > sv[e] ? tm : sv[e];
        tm = max(tm, __shfl_xor(tm, 16, 64));
        tm = max(tm, __shfl_xor(tm, 32, 64));
        int mn = tm > mi ? tm : mi;
        float esc = fexp2(c2 * (float)(mi - mn));
        float es = 0.f;
        #pragma unroll
        for (int e = 0; e < 16; e++) es += fexp2(c2 * (float)(sv[e] - mn));
        es += __shfl_xor(es, 16, 64);
        es += __shfl_xor(es, 32, 64);
        l = l * esc + es;
        mi = mn;
        VMCNT0;
        __syncthreads();
        buf ^= 1;
    }
    float invl = 127.0f / l;
    // ---- pass 2: quantized probs (packed dwords), int8 PV ----
    unsigned* Ps32 = (unsigned*)Qs;        // 16 kdw x 20-dword stride per warp
    int pwr = w * 320;
    v4i of[8];
    #pragma unroll
    for (int nf = 0; nf < 8; nf++) of[nf] = vzero;
    STAGE_K(0, 0);
    STAGE_V(0, 0);
    VMCNT0;
    __syncthreads();
    buf = 0;
    for (int kt = 0; kt <= qb; kt++) {
        if (kt < qb) { STAGE_K(buf ^ 1, kt + 1); STAGE_V(buf ^ 1, kt + 1); }
        v4i sf[4] = {vzero, vzero, vzero, vzero};
        __builtin_amdgcn_s_setprio(1);
        #pragma unroll
        for (int ks = 0; ks < 2; ks++)
            #pragma unroll
            for (int f = 0; f < 4; f++) {
                int row = f * 16 + qlan;
                v4i bk = *(const v4i*)(&Ks[buf][row * 128 + (((ks * 4 + g) ^ (row & 7)) * 16)]);
                sf[f] = __builtin_amdgcn_mfma_i32_16x16x64_i8(bk, aq[ks], sf[f], 0, 0, 0);
            }
        __builtin_amdgcn_s_setprio(0);
        if (kt == qb) {
            int qthr = w * 16 + qlan;
            #pragma unroll
            for (int f = 0; f < 4; f++) {
                unsigned pk = 0;
                #pragma unroll
                for (int r = 0; r < 4; r++) {
                    int kl = f * 16 + g * 4 + r;
                    int s = (kl > qthr) ? NEGS : sf[f][r];
                    float t = fexp2(c2 * (float)(s - mi));
                    int pq = (int)rintf(t * invl);
                    pk |= ((unsigned)pq) << (8 * r);
                }
                Ps32[pwr + (4 * f + g) * 20 + qlan] = pk;
            }
        } else {
            #pragma unroll
            for (int f = 0; f < 4; f++) {
                unsigned pk = 0;
                #pragma unroll
                for (int r = 0; r < 4; r++) {
                    float t = fexp2(c2 * (float)(sf[f][r] - mi));
                    int pq = (int)rintf(t * invl);
                    pk |= ((unsigned)pq) << (8 * r);
                }
                Ps32[pwr + (4 * f + g) * 20 + qlan] = pk;
            }
        }
        int rb = pwr + 80 * g + qlan;
        v4i ap;
        ap[0] = (int)Ps32[rb];
        ap[1] = (int)Ps32[rb + 20];
        ap[2] = (int)Ps32[rb + 40];
        ap[3] = (int)Ps32[rb + 60];
        __builtin_amdgcn_s_setprio(1);
        #pragma unroll
        for (int nf = 0; nf < 8; nf++) {
            int row = nf * 16 + qlan;
            v4i bv = *(const v4i*)(&Vs[buf][row * 64 + ((g ^ (row & 3)) * 16)]);
            of[nf] = __builtin_amdgcn_mfma_i32_16x16x64_i8(ap, bv, of[nf], 0, 0, 0);
        }
        __builtin_amdgcn_s_setprio(0);
        VMCNT0;
        __syncthreads();
        buf ^= 1;
    }
    int mymax = 0;
    #pragma unroll
    for (int nf = 0; nf < 8; nf++)
        #pragma unroll
        for (int r = 0; r < 4; r++) {
            int val = of[nf][r];
            int av = val < 0 ? -val : val;
            mymax = av > mymax ? av : mymax;
            int qg = qb * 64 + w * 16 + 4 * g + r;
            AO[(long)qg * HID + h * 128 + nf * 16 + qlan] = val;
        }
    #pragma unroll
    for (int off = 1; off < 64; off <<= 1) {
        int o2 = __shfl_xor(mymax, off, 64);
        mymax = o2 > mymax ? o2 : mymax;
    }
    if (lane == 0) smx[w] = mymax;
    __syncthreads();
    if (tid == 0) {
        int mm = max(max(smx[0], smx[1]), max(smx[2], smx[3]));
        atomicMax(slots + (8 << 5), (unsigned)mm);
    }
}

// ---------------- quantize attn_out (int32 -> int8), publish absmax to slot 9 ----------------
__global__ void k_quant_ao(const int* __restrict__ a, int8_t* __restrict__ q, unsigned* slots) {
    float sv = slot_scale(slots, 7);
    float spv = (1.0f / 127.0f) * sv;
    float amax = spv * (float)(int)slots[8 << 5];
    float s = fmaxf(amax / 127.0f, 1e-8f);
    long nvec = (long)SEQ * HID / 4;
    for (long vid = blockIdx.x * (long)blockDim.x + threadIdx.x; vid < nvec;
         vid += (long)gridDim.x * blockDim.x) {
        int4 v = *(const int4*)(a + vid * 4);
        int a0 = q8v(spv * (float)v.x, s);
        int a1 = q8v(spv * (float)v.y, s);
        int a2 = q8v(spv * (float)v.z, s);
        int a3 = q8v(spv * (float)v.w, s);
        unsigned pa = (unsigned)(uint8_t)(int8_t)a0
                    | ((unsigned)(uint8_t)(int8_t)a1 << 8)
                    | ((unsigned)(uint8_t)(int8_t)a2 << 16)
                    | ((unsigned)(uint8_t)(int8_t)a3 << 24);
        *(unsigned*)(q + vid * 4) = pa;
    }
    if (blockIdx.x == 0 && threadIdx.x == 0) slots[9 << 5] = __float_as_uint(amax);
}

extern "C" void kernel_launch(void* const* d_in, const int* in_sizes, int n_in,
                              void* d_out, int out_size, void* d_ws, size_t ws_size,
                              hipStream_t stream) {
    (void)in_sizes; (void)n_in; (void)out_size;
    const float* hid = (const float*)d_in[0];
    const int* pos = (const int*)d_in[2];
    const float* wqp = (const float*)d_in[3];
    const float* wkp = (const float*)d_in[4];
    const float* wvp = (const float*)d_in[5];
    const float* wop = (const float*)d_in[6];
    float* out = (float*)d_out;
    char* ws = (char*)d_ws;

    size_t o = 0;
    auto alloc = [&](size_t sz) { size_t r = o; o += (sz + 255) & ~(size_t)255; return r; };
    unsigned* slots = (unsigned*)(ws + alloc(2048));
    int8_t* Xq   = (int8_t*)(ws + alloc((size_t)SEQ * HID));      // later reused as AOq
    int8_t* Wqq  = (int8_t*)(ws + alloc((size_t)HID * HID));      // later reused as Woq
    int8_t* Wkvq = (int8_t*)(ws + alloc((size_t)KVCAT * HID));
    float*  Qf   = (float*)(ws + alloc((size_t)SEQ * HID * 4));   // later reused as AOint
    float*  KVf  = (float*)(ws + alloc((size_t)SEQ * KVCAT * 4));
    int8_t* Qq   = (int8_t*)(ws + alloc((size_t)SEQ * HID));
    int8_t* Kq   = (int8_t*)(ws + alloc((size_t)SEQ * KVDIM));
    int8_t* Vtq  = (int8_t*)(ws + alloc((size_t)KVDIM * SEQ));
    float*  ctab = (float*)(ws + alloc((size_t)SEQ * 64 * 4));
    float*  stab = (float*)(ws + alloc((size_t)SEQ * 64 * 4));
    if (ws_size < o) return;
    int8_t* Woq = Wqq;
    int*    AOint = (int*)Qf;
    int8_t* AOq = Xq;

    hipMemsetAsync(slots, 0, 2048, stream);
    k_ropetab<<<SEQ * 64 / 256, 256, 0, stream>>>(pos, ctab, stab);
    k_absmax5<<<2048, 256, 0, stream>>>(hid, wqp, wkp, wvp, wop, slots);
    k_quant4<<<2048, 256, 0, stream>>>(hid, wqp, wkp, wvp,
                                       Xq, Wqq, Wkvq, Wkvq + (size_t)KVDIM * HID, slots);
    k_gemm_i8<<<512, 256, 0, stream>>>(Xq, Wqq, Qf, SEQ, HID, HID, slots,
                                       0, 1, 1, 1 << 30, -1, 1 << 30);
    k_gemm_i8<<<256, 256, 0, stream>>>(Xq, Wkvq, KVf, SEQ, KVCAT, HID, slots,
                                       0, 2, 3, KVDIM, 7, KVDIM);   // fused V absmax -> slot 7
    const long CALL = 0x3FFFFFFFL;
    k_quant<<<2048, 256, 0, stream>>>(wop, Woq, (long)HID * HID / 4, 40, CALL, 0, slots, 4);
    k_rope<<<1024, 256, 0, stream>>>(Qf, HID, 5, SEQ * NH * 16, ctab, stab, slots, 5);
    k_rope<<<1024, 256, 0, stream>>>(KVf, KVCAT, 3, SEQ * NKV * 16, ctab, stab, slots, 6);
    k_quant<<<2048, 256, 0, stream>>>(Qf, Qq, (long)SEQ * HID / 4, 40, CALL, 0, slots, 5);
    k_quant<<<1024, 256, 0, stream>>>(KVf, Kq, (long)SEQ * KVDIM / 4, 8, 255, KVCAT, slots, 6);
    k_transq<<<dim3(32, 64), 256, 0, stream>>>(KVf + KVDIM, KVCAT, Vtq, SEQ, slots, 7);
    k_attn<<<1024, 256, 0, stream>>>(Qq, Kq, Vtq, AOint, slots);
    k_quant_ao<<<2048, 256, 0, stream>>>(AOint, AOq, slots);
    k_gemm_i8<<<512, 256, 0, stream>>>(AOq, Woq, out, SEQ, HID, HID, slots,
                                       9, 4, 4, 1 << 30, -1, 1 << 30);
}